// Round 20
// baseline (100.723 us; speedup 1.0000x reference)
//
#include <hip/hip_runtime.h>
#include <hip/hip_bf16.h>
#include <math.h>

#define NB 4096   // batch
#define ND 2048   // feature dim
#define BT 256    // output tile (256x256)
#define NTB (NB / BT)            // 16 tile-blocks per dim
#define NBLK (NTB * (NTB + 1) / 2)  // 136 upper-tri blocks (= 8*17)
#define NKT (ND / 64)            // 32 K-tiles of 64
#define TPC 68                   // padded pack row (ushorts)

typedef __attribute__((ext_vector_type(8))) short short8;
typedef __attribute__((ext_vector_type(4))) float floatx4;
typedef __attribute__((ext_vector_type(4))) unsigned short ushort4v;

#define GLOAD_LDS16(g, l) \
  __builtin_amdgcn_global_load_lds((const __attribute__((address_space(1))) void*)(g), \
                                   (__attribute__((address_space(3))) void*)(l), 16, 0, 0)

__device__ __forceinline__ unsigned f2bf(float x) {  // RNE fp32 -> bf16 bits
  unsigned u = __float_as_uint(x);
  return (u + 0x7FFFu + ((u >> 16) & 1u)) >> 16;
}

union H16 { unsigned short u; _Float16 h; };
__device__ __forceinline__ unsigned short f2h(float x) { H16 c; c.h = (_Float16)x; return c.u; }
__device__ __forceinline__ float h2f(unsigned short u) { H16 c; c.u = u; return (float)c.h; }

// ---- kernel 1: L2-normalize rows -> bf16 ----
__global__ __launch_bounds__(256) void norm_kernel(const float* __restrict__ feats,
                                                   unsigned short* __restrict__ fb) {
  int row = blockIdx.x;
  int t = threadIdx.x;
  const float4* src = (const float4*)(feats + (size_t)row * ND);
  float4 v0 = src[t * 2];
  float4 v1 = src[t * 2 + 1];
  float ss = v0.x * v0.x + v0.y * v0.y + v0.z * v0.z + v0.w * v0.w +
             v1.x * v1.x + v1.y * v1.y + v1.z * v1.z + v1.w * v1.w;
  for (int off = 32; off > 0; off >>= 1) ss += __shfl_down(ss, off);
  __shared__ float wsum[4];
  int lane = t & 63, wid = t >> 6;
  if (lane == 0) wsum[wid] = ss;
  __syncthreads();
  float tot = wsum[0] + wsum[1] + wsum[2] + wsum[3];
  float inv = 1.0f / (sqrtf(tot) + 1e-12f);
  uint4 o;
  o.x = f2bf(v0.x * inv) | (f2bf(v0.y * inv) << 16);
  o.y = f2bf(v0.z * inv) | (f2bf(v0.w * inv) << 16);
  o.z = f2bf(v1.x * inv) | (f2bf(v1.y * inv) << 16);
  o.w = f2bf(v1.z * inv) | (f2bf(v1.w * inv) << 16);
  ((uint4*)(fb + (size_t)row * ND))[t] = o;
}

// ---- kernel 2: triangular 256x256 tile (R8-verified K-loop), dual store ----
__global__ __launch_bounds__(512) void pass0_kernel(const unsigned short* __restrict__ fb,
                                                    unsigned short* __restrict__ sim) {
  // 8 half-buffers of 16KB: index (o<<2)|(d<<1)|h ; o:0=A,1=B  d:dbuf  h:row-half
  __shared__ __align__(16) char shraw[131072];

  int tid = threadIdx.x;
  int l = tid & 63, wv = tid >> 6;
  int wm = wv >> 2, wn = wv & 3;   // 2 x 4 wave grid; per-wave 128 rows x 64 cols

  // XCD swizzle (bijective: 136 = 8 * 17) + triangle decode
  int bid = (blockIdx.x & 7) * 17 + (blockIdx.x >> 3);
  int rem = bid, bi = 0;
  while (rem >= NTB - bi) { rem -= NTB - bi; bi++; }
  int bj = bi + rem;
  int row0 = bi * BT, col0 = bj * BT;

  auto lds_half = [&](int o, int d, int h) -> char* {
    return shraw + (size_t)(((o << 2) | (d << 1) | h) << 14);
  };
  // stage one 128x64 half-tile (R8-verified): linear LDS dest, swizzled source
  auto stage = [&](int o, int d, int h, int t) {
#pragma unroll
    for (int e = 0; e < 2; e++) {
      int li = (wv * 2 + e) * 64 + l;
      int r = li >> 3, c = li & 7;
      GLOAD_LDS16(fb + (size_t)(((o ? col0 : row0) + h * 128) + r) * ND + t * 64 + ((c ^ (r & 7)) * 8),
                  lds_half(o, d, h) + (size_t)(wv * 2 + e) * 1024);
    }
  };

  floatx4 acc[8][4];
#pragma unroll
  for (int j = 0; j < 8; j++)
#pragma unroll
    for (int r = 0; r < 4; r++) acc[j][r] = (floatx4){0.f, 0.f, 0.f, 0.f};

  // R8-verified fragment offsets (within a 128-row half): slot = ck ^ (rh&7)
  int offA[4][2], offB[2][2];
#pragma unroll
  for (int jl = 0; jl < 4; jl++) {
    int rh = (2 * jl + wm) * 16 + (l & 15);
#pragma unroll
    for (int ks = 0; ks < 2; ks++) {
      int ck = ks * 4 + (l >> 4);
      offA[jl][ks] = rh * 128 + ((ck ^ (rh & 7)) * 16);
    }
  }
#pragma unroll
  for (int rr = 0; rr < 2; rr++) {
    int rh = (wn + 4 * rr) * 16 + (l & 15);
#pragma unroll
    for (int ks = 0; ks < 2; ks++) {
      int ck = ks * 4 + (l >> 4);
      offB[rr][ks] = rh * 128 + ((ck ^ (rh & 7)) * 16);
    }
  }

  // prologue (R8-verified): tile0 all 4 halves, tile1 {A-h0,B-h0,B-h1}
  stage(0, 0, 0, 0); stage(1, 0, 0, 0); stage(1, 0, 1, 0); stage(0, 0, 1, 0);
  stage(0, 1, 0, 1); stage(1, 1, 0, 1); stage(1, 1, 1, 1);
  asm volatile("s_waitcnt vmcnt(6) lgkmcnt(0)" ::: "memory");
  __builtin_amdgcn_s_barrier();

#define MFMA_CLUSTER(JA, RA, AB, BB)                                              \
  _Pragma("unroll") for (int jl = 0; jl < 4; jl++)                                \
  _Pragma("unroll") for (int rr = 0; rr < 2; rr++) {                              \
    acc[(JA) + jl][(RA) + rr] =                                                   \
        __builtin_amdgcn_mfma_f32_16x16x32_bf16(AB[jl][0], BB[rr][0],             \
                                                acc[(JA) + jl][(RA) + rr], 0, 0, 0); \
    acc[(JA) + jl][(RA) + rr] =                                                   \
        __builtin_amdgcn_mfma_f32_16x16x32_bf16(AB[jl][1], BB[rr][1],             \
                                                acc[(JA) + jl][(RA) + rr], 0, 0, 0); \
  }

  for (int u = 0; u < NKT; u++) {
    int dd = u & 1;
    bool drain = (u >= NKT - 2);
    const char* A0 = lds_half(0, dd, 0);
    const char* A1 = lds_half(0, dd, 1);
    const char* B0 = lds_half(1, dd, 0);
    const char* B1 = lds_half(1, dd, 1);
    short8 a_[4][2], b0_[2][2], b1_[2][2];

    // ---- ph0: read A0,B0,B1 (16); stage A-h1(u+1); MFMA A0xB0 + A0xB1 ----
#pragma unroll
    for (int jl = 0; jl < 4; jl++) {
      a_[jl][0] = *(const short8*)(A0 + offA[jl][0]);
      a_[jl][1] = *(const short8*)(A0 + offA[jl][1]);
    }
#pragma unroll
    for (int rr = 0; rr < 2; rr++) {
      b0_[rr][0] = *(const short8*)(B0 + offB[rr][0]);
      b0_[rr][1] = *(const short8*)(B0 + offB[rr][1]);
      b1_[rr][0] = *(const short8*)(B1 + offB[rr][0]);
      b1_[rr][1] = *(const short8*)(B1 + offB[rr][1]);
    }
    if (u + 1 < NKT) stage(0, 1 - dd, 1, u + 1);
    asm volatile("s_waitcnt lgkmcnt(0)" ::: "memory");
    __builtin_amdgcn_sched_barrier(0);
    __builtin_amdgcn_s_setprio(1);
    MFMA_CLUSTER(0, 0, a_, b0_)
    MFMA_CLUSTER(0, 2, a_, b1_)
    __builtin_amdgcn_s_setprio(0);
    if (drain) asm volatile("s_waitcnt vmcnt(0)" ::: "memory");
    else       asm volatile("s_waitcnt vmcnt(8)" ::: "memory");
    __builtin_amdgcn_s_barrier();

    // ---- ph1: read A1 (8); stage {A-h0,B-h0,B-h1}(u+2); MFMA A1xB1 + A1xB0 ----
#pragma unroll
    for (int jl = 0; jl < 4; jl++) {
      a_[jl][0] = *(const short8*)(A1 + offA[jl][0]);
      a_[jl][1] = *(const short8*)(A1 + offA[jl][1]);
    }
    if (u + 2 < NKT) {
      stage(0, dd, 0, u + 2);
      stage(1, dd, 0, u + 2);
      stage(1, dd, 1, u + 2);
    }
    asm volatile("s_waitcnt lgkmcnt(0)" ::: "memory");
    __builtin_amdgcn_sched_barrier(0);
    __builtin_amdgcn_s_setprio(1);
    MFMA_CLUSTER(4, 2, a_, b1_)
    MFMA_CLUSTER(4, 0, a_, b0_)
    __builtin_amdgcn_s_setprio(0);
    if (drain) asm volatile("s_waitcnt vmcnt(0)" ::: "memory");
    else       asm volatile("s_waitcnt vmcnt(8)" ::: "memory");
    __builtin_amdgcn_s_barrier();
  }

  // element (row_l, col_l): row_l = (2j+wm)*16 + (l>>4)*4 + v  (j=0..7)
  //                         col_l = (wn+4r)*16 + (l&15)        (r=0..3)

  // ---- C^T pack + store -> mirror block [col0, row0], 4 chunks of 64 rows ----
  // chunk h covers orig-rows [64h, 64h+64): j = 2h + jl (jl=0,1), all waves
#pragma unroll
  for (int h = 0; h < 4; h++) {
    __syncthreads();
    unsigned short (*tileT)[TPC] = (unsigned short(*)[TPC])shraw;
#pragma unroll
    for (int jl = 0; jl < 2; jl++) {
      int j = 2 * h + jl;
      int lr = (2 * jl + wm) * 16 + (l >> 4) * 4;   // row within chunk (0..63)
#pragma unroll
      for (int r = 0; r < 4; r++) {
        int C = (wn + 4 * r) * 16 + (l & 15);
        ushort4v pk;
        pk[0] = f2h(acc[j][r][0]);
        pk[1] = f2h(acc[j][r][1]);
        pk[2] = f2h(acc[j][r][2]);
        pk[3] = f2h(acc[j][r][3]);
        *(ushort4v*)(&tileT[C][lr]) = pk;
      }
    }
    __syncthreads();
    int c = tid >> 1, seg = tid & 1;   // 256 cols x 2 threads, 32 elems each
    const unsigned short* srcp = &tileT[c][seg * 32];
    unsigned short* dstp = sim + (size_t)(col0 + c) * NB + row0 + h * 64 + seg * 32;
#pragma unroll
    for (int k = 0; k < 4; k++)
      *(short8*)(dstp + k * 8) = *(const short8*)(srcp + k * 8);
  }

  // ---- direct pack + store -> own block [row0, col0] (off-diagonal only) ----
  // chunk h covers cols [64h, 64h+64): r = h, col-group = wn
  if (bi != bj) {
#pragma unroll
    for (int h = 0; h < 4; h++) {
      __syncthreads();
      unsigned short (*tileR)[TPC] = (unsigned short(*)[TPC])shraw;
#pragma unroll
      for (int j = 0; j < 8; j++) {
        int row_l = (2 * j + wm) * 16 + (l >> 4) * 4;
        int ch = wn * 16 + (l & 15);   // col within chunk (0..63)
#pragma unroll
        for (int v = 0; v < 4; v++)
          tileR[row_l + v][ch] = f2h(acc[j][h][v]);
      }
      __syncthreads();
      int r_ = tid >> 1, seg = tid & 1;
      const unsigned short* srcp = &tileR[r_][seg * 32];
      unsigned short* dstp = sim + (size_t)(row0 + r_) * NB + col0 + h * 64 + seg * 32;
#pragma unroll
      for (int k = 0; k < 4; k++)
        *(short8*)(dstp + k * 8) = *(const short8*)(srcp + k * 8);
    }
  }
}

// ---- kernel 3: fused stats + exp-sums, FOUR waves per row (quarter-row each) ----
__global__ __launch_bounds__(512) void sums_kernel(const unsigned short* __restrict__ sim,
                                                   const int* __restrict__ labels,
                                                   float* __restrict__ gps,
                                                   float* __restrict__ gns) {
  int t = threadIdx.x, l = t & 63, w = t >> 6;   // 8 waves
  int rloc = w >> 2, quarter = w & 3;            // 2 rows/block, 4 waves/row
  int r = blockIdx.x * 2 + rloc;
  int rl = labels[r];
  const unsigned short* row = sim + (size_t)r * NB + quarter * 1024;
  int jbase = quarter * 1024;

  short8 sv[2];
  float pmin = 3.0e38f, nmax = -3.0e38f;
#pragma unroll
  for (int it = 0; it < 2; it++) {
    int j0 = it * 512 + l * 8;
    sv[it] = *(const short8*)(row + j0);
    int4 lb0 = *(const int4*)(labels + jbase + j0);
    int4 lb1 = *(const int4*)(labels + jbase + j0 + 4);
    int lb[8] = {lb0.x, lb0.y, lb0.z, lb0.w, lb1.x, lb1.y, lb1.z, lb1.w};
#pragma unroll
    for (int e = 0; e < 8; e++) {
      float s = h2f((unsigned short)sv[it][e]);
      int j = jbase + j0 + e;
      if (lb[e] == rl) {
        if (j != r && s < 0.99999f) pmin = fminf(pmin, s);
      } else {
        nmax = fmaxf(nmax, s);
      }
    }
  }
#pragma unroll
  for (int off = 1; off < 64; off <<= 1) {
    pmin = fminf(pmin, __shfl_xor(pmin, off));
    nmax = fmaxf(nmax, __shfl_xor(nmax, off));
  }
  // combine the 4 quarter-row waves
  __shared__ float spm[8], snm[8], sps[8], sns[8];
  if (l == 0) { spm[w] = pmin; snm[w] = nmax; }
  __syncthreads();
  int g = w & ~3;
  pmin = fminf(fminf(spm[g], spm[g + 1]), fminf(spm[g + 2], spm[g + 3]));
  nmax = fmaxf(fmaxf(snm[g], snm[g + 1]), fmaxf(snm[g + 2], snm[g + 3]));
  // empty-mask semantics: sentinels keep masks false -> sums 0 -> invalid (matches ref)

  float ps0 = 0.f, ps1 = 0.f, ns0 = 0.f, ns1 = 0.f;
#pragma unroll
  for (int it = 0; it < 2; it++) {
    int j0 = it * 512 + l * 8;
    int4 lb0 = *(const int4*)(labels + jbase + j0);
    int4 lb1 = *(const int4*)(labels + jbase + j0 + 4);
    int lb[8] = {lb0.x, lb0.y, lb0.z, lb0.w, lb1.x, lb1.y, lb1.z, lb1.w};
#pragma unroll
    for (int e = 0; e < 8; e++) {
      float s = h2f((unsigned short)sv[it][e]);
      int j = jbase + j0 + e;
      float pv = 0.f, nv = 0.f;
      if (lb[e] == rl) {
        if (j != r && s < 0.99999f && (s - 0.1f < nmax)) pv = __expf(-2.0f * (s - 0.5f));
      } else {
        if (s + 0.1f > pmin) nv = __expf(40.0f * (s - 0.5f));
      }
      if (e & 1) { ps1 += pv; ns1 += nv; }
      else       { ps0 += pv; ns0 += nv; }
    }
  }
  float ps = ps0 + ps1, ns = ns0 + ns1;
  for (int off = 32; off > 0; off >>= 1) {
    ps += __shfl_down(ps, off);
    ns += __shfl_down(ns, off);
  }
  if (l == 0) { sps[w] = ps; sns[w] = ns; }
  __syncthreads();
  if (t < 2) {
    gps[blockIdx.x * 2 + t] = sps[4 * t] + sps[4 * t + 1] + sps[4 * t + 2] + sps[4 * t + 3];
    gns[blockIdx.x * 2 + t] = sns[4 * t] + sns[4 * t + 1] + sns[4 * t + 2] + sns[4 * t + 3];
  }
}

// ---- kernel 4: finalize scalar loss ----
__global__ __launch_bounds__(256) void finalize_kernel(const float* __restrict__ gps,
                                                       const float* __restrict__ gns,
                                                       float* __restrict__ out) {
  int t = threadIdx.x;
  float sum = 0.f;
  for (int i = t; i < NB; i += 256) {
    float ps = gps[i], ns = gns[i];
    if (ps > 0.f && ns > 0.f) sum += 0.5f * log1pf(ps) + 0.025f * log1pf(ns);
  }
  for (int off = 32; off > 0; off >>= 1) sum += __shfl_down(sum, off);
  __shared__ float wsum[4];
  int lane = t & 63, wid = t >> 6;
  if (lane == 0) wsum[wid] = sum;
  __syncthreads();
  if (t == 0) out[0] = (wsum[0] + wsum[1] + wsum[2] + wsum[3]) / (float)NB;
}

extern "C" void kernel_launch(void* const* d_in, const int* in_sizes, int n_in,
                              void* d_out, int out_size, void* d_ws, size_t ws_size,
                              hipStream_t stream) {
  const float* feats = (const float*)d_in[0];
  const int* labels = (const int*)d_in[1];

  char* ws = (char*)d_ws;
  unsigned short* fb = (unsigned short*)ws;                  // 16 MB bf16 normalized feats
  size_t off = (size_t)NB * ND * 2;
  unsigned short* sim = (unsigned short*)(ws + off);         // 32 MB fp16 sim (full)
  off += (size_t)NB * NB * 2;
  float* gps = (float*)(ws + off); off += NB * 4;
  float* gns = (float*)(ws + off); off += NB * 4;

  norm_kernel<<<NB, 256, 0, stream>>>(feats, fb);
  pass0_kernel<<<NBLK, 512, 0, stream>>>(fb, sim);
  sums_kernel<<<NB / 2, 512, 0, stream>>>(sim, labels, gps, gns);
  finalize_kernel<<<1, 256, 0, stream>>>(gps, gns, (float*)d_out);
}